// Round 11
// baseline (317.388 us; speedup 1.0000x reference)
//
#include <hip/hip_runtime.h>
#include <cmath>

#define SQ 4096
#define SK 4096
#define NH 16
#define DH 128
#define TQ 64
#define TK 64
#define TOPK 2048
#define NEG_SENTINEL (-3.0e38f)

typedef __attribute__((ext_vector_type(8))) short short8;
typedef __attribute__((ext_vector_type(4))) float f32x4;
typedef __attribute__((ext_vector_type(16))) float f32x16;

#define QS_BYTES ((size_t)64 * 16 * 2 * 1024 * 16)   // [qtile][head][part][unit16B]

// Split f32 x into bf16 hi + bf16 lo (truncation split; residual exact).
__device__ __forceinline__ void cvt8(const float4 x0, const float4 x1,
                                     short8& hv, short8& lv) {
    const float xs[8] = {x0.x, x0.y, x0.z, x0.w, x1.x, x1.y, x1.z, x1.w};
    #pragma unroll
    for (int j = 0; j < 8; ++j) {
        const unsigned int b = __float_as_uint(xs[j]);
        const float hf = __uint_as_float(b & 0xFFFF0000u);
        const float r = xs[j] - hf;
        hv[j] = (short)(b >> 16);
        lv[j] = (short)(__float_as_uint(r) >> 16);
    }
}

__device__ __forceinline__ void gload_lds16(const void* g, void* l) {
    __builtin_amdgcn_global_load_lds(
        (const __attribute__((address_space(1))) unsigned int*)g,
        (__attribute__((address_space(3))) unsigned int*)l,
        16, 0, 0);
}

// ---------------------------------------------------------------------------
// Kernel 0: pre-split Q (validated round 6/7, unchanged).
// ---------------------------------------------------------------------------
__global__ __launch_bounds__(256) void split_q_kernel(
    const float* __restrict__ qg,    // [SQ][NH][DH]
    short8* __restrict__ qs)         // [64][16][2][1024] 16B units
{
    const int gidx = blockIdx.x * 256 + threadIdx.x;   // [row][h][c]
    const int c   = gidx & 15;
    const int h   = (gidx >> 4) & 15;
    const int row = gidx >> 8;
    const size_t gb = ((size_t)row * NH + h) * DH + c * 8;
    const float4 x0 = *(const float4*)&qg[gb];
    const float4 x1 = *(const float4*)&qg[gb + 4];
    short8 hv, lv;
    cvt8(x0, x1, hv, lv);
    const int tile = row >> 6;
    const int r    = row & 63;
    const int u    = c * 64 + (r ^ (c & 7));
    const size_t base = (size_t)(tile * 16 + h) * 2048;
    qs[base + u]        = hv;
    qs[base + 1024 + u] = lv;
}

// ---------------------------------------------------------------------------
// Kernel 1: scores — round-6 staging structure, MFMA shape 32x32x16.
// Wave = one 32x32 tile (wr = q-half, wc = k-half). A/B operand: lane l holds
// row/col = l&31, k = (l>>5)*8 + j  => chunk c = 2s + (l>>5) for k-step s.
// C layout: col = l&31, row = (reg&3) + 8*(reg>>2) + 4*(l>>5)  [m74/m101].
// 3-term split (hh + hl + lh). LDS 36KB -> 4 blocks/CU.
// ---------------------------------------------------------------------------
__global__ __launch_bounds__(256, 4) void scores_kernel(
    const short8* __restrict__ qs,   // pre-split Q
    const float* __restrict__ kg,    // [SK][DH]
    const float* __restrict__ wg,    // [SQ][NH]
    float* __restrict__ scores)      // [SQ][SK]
{
    const int bk = blockIdx.x;
    const int bq = blockIdx.y;
    const int qbase = bq * TQ;
    const int kbase = bk * TK;
    const int tid = threadIdx.x;

    if (bk > bq) {
        const float4 minf = make_float4(NEG_SENTINEL, NEG_SENTINEL, NEG_SENTINEL, NEG_SENTINEL);
        #pragma unroll
        for (int it = 0; it < 4; ++it) {
            int idx = it * 256 + tid;
            int r  = idx >> 4;
            int c4 = idx & 15;
            *(float4*)&scores[(size_t)(qbase + r) * SK + kbase + (c4 << 2)] = minf;
        }
        return;
    }

    __shared__ short8 QsH[1024], QsL[1024];   // 16KB + 16KB
    __shared__ float  Wl[TQ * NH];            // 4KB

    const int lane = tid & 63;
    const int wid  = tid >> 6;
    const int wr   = wid >> 1;     // q-half
    const int wc   = wid & 1;      // k-half
    const int l31  = lane & 31;
    const int hi5  = lane >> 5;    // 0/1

    #pragma unroll
    for (int it = 0; it < 4; ++it) {
        const int i = tid + it * 256;
        Wl[i] = wg[(size_t)qbase * NH + i] * 0.08838834764831845f;
    }

    // ---- K fragments in registers (once per block): col = l31, 8 k-steps ----
    short8 bh[8], bl[8];
    {
        const int kcol = kbase + wc * 32 + l31;
        #pragma unroll
        for (int s = 0; s < 8; ++s) {
            const int c = 2 * s + hi5;
            const float4 x0 = *(const float4*)&kg[(size_t)kcol * DH + c * 8];
            const float4 x1 = *(const float4*)&kg[(size_t)kcol * DH + c * 8 + 4];
            cvt8(x0, x1, bh[s], bl[s]);
        }
    }

    // A-fragment LDS unit offsets
    int uo[8];
    {
        const int row = wr * 32 + l31;
        #pragma unroll
        for (int s = 0; s < 8; ++s) {
            const int c = 2 * s + hi5;
            uo[s] = c * 64 + (row ^ (c & 7));
        }
    }

    f32x16 sacc;
    #pragma unroll
    for (int j = 0; j < 16; ++j) sacc[j] = 0.0f;

    for (int h = 0; h < NH; ++h) {
        __syncthreads();   // h=0: Wl visible; h>0: previous readers done
        {
            const short8* hb = qs + (size_t)(bq * 16 + h) * 2048;
            #pragma unroll
            for (int cc = 0; cc < 4; ++cc) {
                const int c = wid * 4 + cc;
                gload_lds16(hb + c * 64 + lane,        &QsH[c * 64]);
                gload_lds16(hb + 1024 + c * 64 + lane, &QsL[c * 64]);
            }
        }
        __syncthreads();   // drains vmcnt -> staged data visible

        f32x16 lac;
        #pragma unroll
        for (int j = 0; j < 16; ++j) lac[j] = 0.0f;

        #pragma unroll
        for (int s = 0; s < 8; ++s) {
            const short8 ah = QsH[uo[s]];
            const short8 al = QsL[uo[s]];
            lac = __builtin_amdgcn_mfma_f32_32x32x16_bf16(ah, bh[s], lac, 0, 0, 0);
            lac = __builtin_amdgcn_mfma_f32_32x32x16_bf16(ah, bl[s], lac, 0, 0, 0);
            lac = __builtin_amdgcn_mfma_f32_32x32x16_bf16(al, bh[s], lac, 0, 0, 0);
        }

        // epilogue: sacc += w' * relu(logits); Wl read is lane-uniform (bcast)
        #pragma unroll
        for (int j = 0; j < 16; ++j) {
            const int row = wr * 32 + (j & 3) + 8 * (j >> 2) + 4 * hi5;
            const float wv = Wl[row * NH + h];
            sacc[j] = fmaf(wv, fmaxf(lac[j], 0.f), sacc[j]);
        }
    }

    // ---- store with causal mask ----
    #pragma unroll
    for (int j = 0; j < 16; ++j) {
        const int q  = qbase + wr * 32 + (j & 3) + 8 * (j >> 2) + 4 * hi5;
        const int kk = kbase + wc * 32 + l31;
        scores[(size_t)q * SK + kk] = (kk <= q) ? sacc[j] : NEG_SENTINEL;
    }
}

// ---------------------------------------------------------------------------
// Kernel 2a: rows 0..2047 — sorted 2048-prefix bitonic (validated, unchanged).
// ---------------------------------------------------------------------------
#define REG_PASS(J)                                                        \
    {                                                                      \
        _Pragma("unroll")                                                  \
        for (int r = 0; r < 16; ++r) {                                     \
            if ((r & (J)) == 0) {                                          \
                const int i = (t << 4) | r;                                \
                const bool up = ((i & k) == 0);                            \
                const unsigned long long a = key[r], b = key[r | (J)];     \
                const unsigned long long mx = a > b ? a : b;               \
                const unsigned long long mn = a > b ? b : a;               \
                key[r]       = up ? mx : mn;                               \
                key[r | (J)] = up ? mn : mx;                               \
            }                                                              \
        }                                                                  \
    }

template<int N>
__global__ __launch_bounds__(N / 16) void topk_kernel(
    const float* __restrict__ scores,
    float* __restrict__ out_idx,
    int row_base)
{
    __shared__ unsigned long long lds[N];

    const int qrow = row_base + blockIdx.x;
    const int t = threadIdx.x;
    const int sw = t & 15;

    unsigned long long key[16];
    {
        const float* rowp = scores + (size_t)qrow * SK + (t << 4);
        #pragma unroll
        for (int r4 = 0; r4 < 4; ++r4) {
            const float4 v = *(const float4*)(rowp + r4 * 4);
            const float vs[4] = {v.x, v.y, v.z, v.w};
            #pragma unroll
            for (int rr = 0; rr < 4; ++rr) {
                const int r = r4 * 4 + rr;
                const int i = (t << 4) | r;
                const unsigned int b = __float_as_uint(vs[rr]);
                const unsigned int u = (b & 0x80000000u) ? ~b : (b | 0x80000000u);
                key[r] = ((unsigned long long)u << 32) | (unsigned int)(4095 - i);
            }
        }
    }

    for (int k = 2; k <= N; k <<= 1) {
        for (int j = k >> 1; j >= 1024; j >>= 1) {
            __syncthreads();
            #pragma unroll
            for (int r = 0; r < 16; ++r) lds[(t << 4) | (r ^ sw)] = key[r];
            __syncthreads();
            #pragma unroll
            for (int r = 0; r < 16; ++r) {
                const int i = (t << 4) | r;
                const unsigned long long bb = lds[(((t << 4) | (r ^ sw))) ^ j];
                const bool take_max = (((i & k) == 0) == ((i & j) == 0));
                const bool agtb = key[r] > bb;
                key[r] = (take_max == agtb) ? key[r] : bb;
            }
        }
        {
            const int j0 = (k >> 1) < 512 ? (k >> 1) : 512;
            for (int j = j0; j >= 16; j >>= 1) {
                #pragma unroll
                for (int r = 0; r < 16; ++r) {
                    const int i = (t << 4) | r;
                    const unsigned long long bb =
                        (unsigned long long)__shfl_xor((long long)key[r], j >> 4, 64);
                    const bool take_max = (((i & k) == 0) == ((i & j) == 0));
                    const bool agtb = key[r] > bb;
                    key[r] = (take_max == agtb) ? key[r] : bb;
                }
            }
        }
        if (k > 8) REG_PASS(8)
        if (k > 4) REG_PASS(4)
        if (k > 2) REG_PASS(2)
        REG_PASS(1)
    }

    if (t < 128) {
        #pragma unroll
        for (int r4 = 0; r4 < 4; ++r4) {
            float4 o;
            o.x = (float)(4095u - (unsigned int)(key[r4 * 4 + 0] & 0xFFFFFFFFu));
            o.y = (float)(4095u - (unsigned int)(key[r4 * 4 + 1] & 0xFFFFFFFFu));
            o.z = (float)(4095u - (unsigned int)(key[r4 * 4 + 2] & 0xFFFFFFFFu));
            o.w = (float)(4095u - (unsigned int)(key[r4 * 4 + 3] & 0xFFFFFFFFu));
            *(float4*)&out_idx[(size_t)qrow * TOPK + (t << 4) + r4 * 4] = o;
        }
    }
}

// ---------------------------------------------------------------------------
// Kernel 2b: rows 2048..4095 — ATOMIC-FREE binary-search select of the
// 2048th-largest u, stable compaction (value desc, index asc), then bitonic
// sort of the 2048 selected keys. Sentinel u < 0x80000000 <= search range,
// so sentinels are excluded automatically.
// ---------------------------------------------------------------------------
#define REG8(J)                                                            \
    {                                                                      \
        _Pragma("unroll")                                                  \
        for (int r = 0; r < 8; ++r) {                                      \
            if ((r & (J)) == 0) {                                          \
                const int i = (t << 3) | r;                                \
                const bool up = ((i & k) == 0);                            \
                const unsigned long long a = key[r], b = key[r | (J)];     \
                const unsigned long long mx = a > b ? a : b;               \
                const unsigned long long mn = a > b ? b : a;               \
                key[r]       = up ? mx : mn;                               \
                key[r | (J)] = up ? mn : mx;                               \
            }                                                              \
        }                                                                  \
    }

__global__ __launch_bounds__(256) void topk_select_kernel(
    const float* __restrict__ scores,
    float* __restrict__ out_idx,
    int row_base)
{
    __shared__ unsigned long long cld[2048];   // 16KB: compaction + LDS exchange
    __shared__ unsigned int wsum[4];

    const int qrow = row_base + blockIdx.x;
    const int t    = threadIdx.x;
    const int lane = t & 63;
    const int wid  = t >> 6;

    // ---- load + monotone transform ----
    unsigned int u[16];
    {
        const float* rowp = scores + (size_t)qrow * SK + (t << 4);
        #pragma unroll
        for (int r4 = 0; r4 < 4; ++r4) {
            const float4 v = *(const float4*)(rowp + r4 * 4);
            const float vs[4] = {v.x, v.y, v.z, v.w};
            #pragma unroll
            for (int rr = 0; rr < 4; ++rr) {
                const unsigned int b = __float_as_uint(vs[rr]);
                u[r4 * 4 + rr] = (b & 0x80000000u) ? ~b : (b | 0x80000000u);
            }
        }
    }

    // ---- binary search: Tu = 2048th-largest u among valid entries ----
    // Valid scores >= 0 -> u >= 0x80000000; rows here have >= 2049 valid.
    unsigned int lo = 0x80000000u, hi = 0xFFFFFFFFu;
    while (lo < hi) {
        const unsigned int mid = lo + ((hi - lo) >> 1) + 1u;   // upper mid
        unsigned int c = 0;
        #pragma unroll
        for (int r = 0; r < 16; ++r) c += (u[r] >= mid) ? 1u : 0u;
        #pragma unroll
        for (int d = 32; d >= 1; d >>= 1) c += __shfl_xor(c, d, 64);
        if (lane == 0) wsum[wid] = c;
        __syncthreads();
        const unsigned int tot = wsum[0] + wsum[1] + wsum[2] + wsum[3];
        __syncthreads();   // protect wsum before next iteration's write
        if (tot >= 2048u) lo = mid; else hi = mid - 1u;
    }
    const unsigned int Tu = lo;

    // count_gt(Tu)
    unsigned int count_gt;
    {
        unsigned int c = 0;
        #pragma unroll
        for (int r = 0; r < 16; ++r) c += (u[r] > Tu) ? 1u : 0u;
        #pragma unroll
        for (int d = 32; d >= 1; d >>= 1) c += __shfl_xor(c, d, 64);
        if (lane == 0) wsum[wid] = c;
        __syncthreads();
        count_gt = wsum[0] + wsum[1] + wsum[2] + wsum[3];
        __syncthreads();
    }
    const unsigned int need = 2048u - count_gt;

    // ---- stable exclusive prefixes (ascending index) of (gt, eq) ----
    unsigned int gtb[16], eqb[16];
    unsigned int cgt = 0, ceq = 0;
    #pragma unroll
    for (int r = 0; r < 16; ++r) {
        gtb[r] = cgt; eqb[r] = ceq;
        cgt += (u[r] > Tu) ? 1u : 0u;
        ceq += (u[r] == Tu) ? 1u : 0u;
    }
    unsigned int pack = (cgt << 16) | ceq;
    unsigned int inc = pack;
    #pragma unroll
    for (int d = 1; d < 64; d <<= 1) {
        const unsigned int v = __shfl_up(inc, d, 64);
        if (lane >= d) inc += v;
    }
    const unsigned int ex = inc - pack;
    if (lane == 63) wsum[wid] = inc;
    __syncthreads();
    unsigned int wex = 0;
    #pragma unroll
    for (int ww = 0; ww < 4; ++ww) wex += (ww < wid) ? wsum[ww] : 0u;
    const unsigned int gt0 = (wex >> 16) + (ex >> 16);
    const unsigned int eq0 = (wex & 0xFFFFu) + (ex & 0xFFFFu);

    // ---- compact selected 2048 keys into cld ----
    #pragma unroll
    for (int r = 0; r < 16; ++r) {
        const unsigned int g = gt0 + gtb[r];
        const unsigned int e = eq0 + eqb[r];
        const int i = (t << 4) | r;
        const unsigned long long kk =
            ((unsigned long long)u[r] << 32) | (unsigned int)(4095 - i);
        if (u[r] > Tu) {
            cld[g + (e < need ? e : need)] = kk;
        } else if (u[r] == Tu && e < need) {
            cld[g + e] = kk;
        }
    }
    __syncthreads();

    // ---- bitonic sort 2048 keys, 256 threads x 8/thread (i = t*8 + r) ----
    unsigned long long key[8];
    #pragma unroll
    for (int r = 0; r < 8; ++r) key[r] = cld[(t << 3) | r];

    const int sw8 = t & 7;
    for (int k = 2; k <= 2048; k <<= 1) {
        for (int j = k >> 1; j >= 512; j >>= 1) {
            __syncthreads();
            #pragma unroll
            for (int r = 0; r < 8; ++r) cld[(t << 3) | (r ^ sw8)] = key[r];
            __syncthreads();
            #pragma unroll
            for (int r = 0; r < 8; ++r) {
                const int i = (t << 3) | r;
                const unsigned long long bb = cld[(((t << 3) | (r ^ sw8))) ^ j];
                const bool take_max = (((i & k) == 0) == ((i & j) == 0));
                const bool agtb = key[r] > bb;
                key[r] = (take_max == agtb) ? key[r] : bb;
            }
        }
        {
            const int j0 = (k >> 1) < 256 ? (k >> 1) : 256;
            for (int j = j0; j >= 8; j >>= 1) {
                #pragma unroll
                for (int r = 0; r < 8; ++r) {
                    const int i = (t << 3) | r;
                    const unsigned long long bb =
                        (unsigned long long)__shfl_xor((long long)key[r], j >> 3, 64);
                    const bool take_max = (((i & k) == 0) == ((i & j) == 0));
                    const bool agtb = key[r] > bb;
                    key[r] = (take_max == agtb) ? key[r] : bb;
                }
            }
        }
        if (k > 4) REG8(4)
        if (k > 2) REG8(2)
        REG8(1)
    }

    // ---- emit 2048 indices ----
    #pragma unroll
    for (int r2 = 0; r2 < 2; ++r2) {
        float4 o;
        o.x = (float)(4095u - (unsigned int)(key[r2 * 4 + 0] & 0xFFFFFFFFu));
        o.y = (float)(4095u - (unsigned int)(key[r2 * 4 + 1] & 0xFFFFFFFFu));
        o.z = (float)(4095u - (unsigned int)(key[r2 * 4 + 2] & 0xFFFFFFFFu));
        o.w = (float)(4095u - (unsigned int)(key[r2 * 4 + 3] & 0xFFFFFFFFu));
        *(float4*)&out_idx[(size_t)qrow * TOPK + (t << 3) + r2 * 4] = o;
    }
}

extern "C" void kernel_launch(void* const* d_in, const int* in_sizes, int n_in,
                              void* d_out, int out_size, void* d_ws, size_t ws_size,
                              hipStream_t stream) {
    const float* q = (const float*)d_in[0];
    const float* k = (const float*)d_in[1];
    const float* w = (const float*)d_in[2];

    float* out        = (float*)d_out;
    float* out_topk   = out;
    float* out_scores = out + (size_t)SQ * TOPK;

    short8* qs = (ws_size >= QS_BYTES) ? (short8*)d_ws : (short8*)out_topk;

    split_q_kernel<<<SQ * NH * 16 / 256, 256, 0, stream>>>(q, qs);

    scores_kernel<<<dim3(SK / TK, SQ / TQ), 256, 0, stream>>>(qs, k, w, out_scores);

    topk_kernel<2048><<<2048, 128, 0, stream>>>(out_scores, out_topk, 0);
    topk_select_kernel<<<2048, 256, 0, stream>>>(out_scores, out_topk, 2048);
}